// Round 1
// baseline (1474.040 us; speedup 1.0000x reference)
//
#include <hip/hip_runtime.h>
#include <hip/hip_bf16.h>
#include <math.h>

#define BZ 16
#define NN 1024
#define FF 1024
#define ALPHA 0.2f
#define NEG_INF (-9e15f)

__device__ inline float waveReduceSum(float v) {
    for (int o = 32; o; o >>= 1) v += __shfl_down(v, o);
    return v;
}
__device__ inline float waveReduceMax(float v) {
    for (int o = 32; o; o >>= 1) v = fmaxf(v, __shfl_down(v, o));
    return v;
}

// ---------------------------------------------------------------------------
// Batched GEMM: C[b] = A[b] @ B[b]   (row-major), optional elu epilogue.
// 64x64 tile, BK=16, 256 threads, 4x4 per thread.
// ---------------------------------------------------------------------------
__global__ __launch_bounds__(256) void gemm_nn(
    const float* __restrict__ A, const float* __restrict__ B, float* __restrict__ C,
    size_t strideA, size_t strideB, size_t strideC, int K, int Ncols, int doElu)
{
    const int b = blockIdx.z;
    const int tileM = blockIdx.y * 64;
    const int tileN = blockIdx.x * 64;
    const float* Ab = A + (size_t)b * strideA;
    const float* Bb = B + (size_t)b * strideB;
    float* Cb = C + (size_t)b * strideC;

    __shared__ float As[64][17];
    __shared__ float Bs[16][65];

    const int tx = threadIdx.x & 15;
    const int ty = threadIdx.x >> 4;

    float acc[4][4];
    #pragma unroll
    for (int i = 0; i < 4; ++i)
        #pragma unroll
        for (int j = 0; j < 4; ++j) acc[i][j] = 0.f;

    for (int k0 = 0; k0 < K; k0 += 16) {
        #pragma unroll
        for (int l = 0; l < 4; ++l) {
            int idx = threadIdx.x + l * 256;
            int r = idx >> 4, c = idx & 15;
            As[r][c] = Ab[(size_t)(tileM + r) * K + k0 + c];
        }
        #pragma unroll
        for (int l = 0; l < 4; ++l) {
            int idx = threadIdx.x + l * 256;
            int r = idx >> 6, c = idx & 63;
            Bs[r][c] = Bb[(size_t)(k0 + r) * Ncols + tileN + c];
        }
        __syncthreads();
        #pragma unroll
        for (int kk = 0; kk < 16; ++kk) {
            float av[4], bv[4];
            #pragma unroll
            for (int i = 0; i < 4; ++i) av[i] = As[ty * 4 + i][kk];
            #pragma unroll
            for (int j = 0; j < 4; ++j) bv[j] = Bs[kk][tx * 4 + j];
            #pragma unroll
            for (int i = 0; i < 4; ++i)
                #pragma unroll
                for (int j = 0; j < 4; ++j) acc[i][j] += av[i] * bv[j];
        }
        __syncthreads();
    }

    #pragma unroll
    for (int i = 0; i < 4; ++i) {
        #pragma unroll
        for (int j = 0; j < 4; ++j) {
            float v = acc[i][j];
            if (doElu) v = (v > 0.f) ? v : expm1f(v);
            Cb[(size_t)(tileM + ty * 4 + i) * Ncols + tileN + tx * 4 + j] = v;
        }
    }
}

// ---------------------------------------------------------------------------
// v = csk_W^T @ a2   for SS and DS.  grid: 4 blocks x 256 threads.
// ---------------------------------------------------------------------------
__global__ __launch_bounds__(256) void prep_v(
    const float* __restrict__ cskW, const float* __restrict__ aSS,
    const float* __restrict__ aDS, float* __restrict__ vSS, float* __restrict__ vDS)
{
    int g = blockIdx.x * 256 + threadIdx.x;
    float accS = 0.f, accD = 0.f;
    for (int f = 0; f < FF; ++f) {
        float w = cskW[(size_t)f * FF + g];
        accS += w * aSS[FF + f];
        accD += w * aDS[FF + f];
    }
    vSS[g] = accS;
    vDS[g] = accD;
}

// c = csk_b . a2 for SS and DS. 1 block.
__global__ __launch_bounds__(256) void prep_c(
    const float* __restrict__ cskb, const float* __restrict__ aSS,
    const float* __restrict__ aDS, float* __restrict__ cv)
{
    int t = threadIdx.x;
    float cS = 0.f, cD = 0.f;
    for (int f = t; f < FF; f += 256) {
        float bb = cskb[f];
        cS += bb * aSS[FF + f];
        cD += bb * aDS[FF + f];
    }
    cS = waveReduceSum(cS);
    cD = waveReduceSum(cD);
    __shared__ float rA[4], rB[4];
    int wid = t >> 6;
    if ((t & 63) == 0) { rA[wid] = cS; rB[wid] = cD; }
    __syncthreads();
    if (t == 0) {
        cv[0] = rA[0] + rA[1] + rA[2] + rA[3];
        cv[1] = rB[0] + rB[1] + rB[2] + rB[3];
    }
}

// ---------------------------------------------------------------------------
// Per-row score GEMVs: one block per (b,i) row.
// sSrcSS = Wh.a1SS ; sDstSS = Wh.a2SS + hx.vSS + cSS ; same for DS with ho.
// ---------------------------------------------------------------------------
__global__ __launch_bounds__(256) void row_scores(
    const float* __restrict__ Wh, const float* __restrict__ hx, const float* __restrict__ ho,
    const float* __restrict__ aSS, const float* __restrict__ aDS,
    const float* __restrict__ vSS, const float* __restrict__ vDS,
    const float* __restrict__ cv,
    float* __restrict__ sSrcSS, float* __restrict__ sDstSS,
    float* __restrict__ sSrcDS, float* __restrict__ sDstDS)
{
    const int row = blockIdx.x;   // b*N + i
    const float* whr = Wh + (size_t)row * FF;
    const float* hxr = hx + (size_t)row * FF;
    const float* hor = ho + (size_t)row * FF;
    const int t = threadIdx.x;

    float d0 = 0.f, d1 = 0.f, d2 = 0.f, d3 = 0.f, d4 = 0.f, d5 = 0.f;
    for (int k = t; k < FF; k += 256) {
        float w = whr[k];
        d0 += w * aSS[k];
        d1 += w * aSS[FF + k];
        d2 += w * aDS[k];
        d3 += w * aDS[FF + k];
        d4 += hxr[k] * vSS[k];
        d5 += hor[k] * vDS[k];
    }
    d0 = waveReduceSum(d0); d1 = waveReduceSum(d1); d2 = waveReduceSum(d2);
    d3 = waveReduceSum(d3); d4 = waveReduceSum(d4); d5 = waveReduceSum(d5);

    __shared__ float red[4][6];
    int wid = t >> 6;
    if ((t & 63) == 0) {
        red[wid][0] = d0; red[wid][1] = d1; red[wid][2] = d2;
        red[wid][3] = d3; red[wid][4] = d4; red[wid][5] = d5;
    }
    __syncthreads();
    if (t == 0) {
        float s0 = 0, s1 = 0, s2 = 0, s3 = 0, s4 = 0, s5 = 0;
        for (int w = 0; w < 4; ++w) {
            s0 += red[w][0]; s1 += red[w][1]; s2 += red[w][2];
            s3 += red[w][3]; s4 += red[w][4]; s5 += red[w][5];
        }
        sSrcSS[row] = s0;
        sDstSS[row] = s1 + s4 + cv[0];
        sSrcDS[row] = s2;
        sDstDS[row] = s3 + s5 + cv[1];
    }
}

// ---------------------------------------------------------------------------
// Row softmax -> att.  One block per row; each thread owns j = t, t+256, ...
// ---------------------------------------------------------------------------
__global__ __launch_bounds__(256) void softmax_att(
    const float* __restrict__ mx, const float* __restrict__ mo,
    const float* __restrict__ sSrcSS, const float* __restrict__ sDstSS,
    const float* __restrict__ sSrcDS, const float* __restrict__ sDstDS,
    float* __restrict__ att)
{
    const int row = blockIdx.x;       // b*N + i
    const int base = row & ~(NN - 1); // b*N
    const int t = threadIdx.x;
    const float srcS = sSrcSS[row];
    const float srcD = sSrcDS[row];
    const float* mxr = mx + (size_t)row * NN;
    const float* mor = mo + (size_t)row * NN;

    float ev[4];
    float m = -INFINITY;
    #pragma unroll
    for (int l = 0; l < 4; ++l) {
        int j = t + l * 256;
        float mxv = mxr[j], mov = mor[j];
        float eS = srcS + sDstSS[base + j];
        float lS = (eS >= 0.f) ? eS : ALPHA * eS;
        float eD = srcD + sDstDS[base + j];
        float lD = (eD >= 0.f) ? eD : ALPHA * eD;
        float val = (mxv > 0.f) ? (lS * mxv + lD * mov) : NEG_INF;
        ev[l] = val;
        m = fmaxf(m, val);
    }
    m = waveReduceMax(m);
    __shared__ float redA[4], redB[4];
    int wid = t >> 6;
    if ((t & 63) == 0) redA[wid] = m;
    __syncthreads();
    float bm = fmaxf(fmaxf(redA[0], redA[1]), fmaxf(redA[2], redA[3]));

    float s = 0.f;
    #pragma unroll
    for (int l = 0; l < 4; ++l) {
        float p = expf(ev[l] - bm);
        ev[l] = p;
        s += p;
    }
    s = waveReduceSum(s);
    if ((t & 63) == 0) redB[wid] = s;
    __syncthreads();
    float bs = redB[0] + redB[1] + redB[2] + redB[3];
    float inv = 1.f / bs;

    float* ar = att + (size_t)row * NN;
    #pragma unroll
    for (int l = 0; l < 4; ++l) ar[t + l * 256] = ev[l] * inv;
}

// ---------------------------------------------------------------------------
extern "C" void kernel_launch(void* const* d_in, const int* in_sizes, int n_in,
                              void* d_out, int out_size, void* d_ws, size_t ws_size,
                              hipStream_t stream)
{
    const float* h    = (const float*)d_in[0];
    const float* hx   = (const float*)d_in[1];
    const float* ho   = (const float*)d_in[2];
    const float* mx   = (const float*)d_in[3];
    const float* mo   = (const float*)d_in[4];
    const float* W    = (const float*)d_in[5];
    const float* aSS  = (const float*)d_in[6];
    const float* aDS  = (const float*)d_in[7];
    const float* cskW = (const float*)d_in[8];
    const float* cskb = (const float*)d_in[9];
    float* out = (float*)d_out;

    float* ws = (float*)d_ws;
    const size_t BIG = (size_t)BZ * NN * FF; // 16M floats
    float* Wh     = ws;
    float* att    = Wh + BIG;
    float* vSS    = att + BIG;
    float* vDS    = vSS + FF;
    float* cv     = vDS + FF;
    float* sSrcSS = cv + 16;
    float* sDstSS = sSrcSS + BZ * NN;
    float* sSrcDS = sDstSS + BZ * NN;
    float* sDstDS = sSrcDS + BZ * NN;

    dim3 gridG(NN / 64, NN / 64, BZ);

    // 1) Wh = h @ W
    gemm_nn<<<gridG, 256, 0, stream>>>(h, W, Wh, (size_t)NN * FF, 0, (size_t)NN * FF,
                                       FF, FF, 0);
    // 2) v vectors + c scalars
    prep_v<<<4, 256, 0, stream>>>(cskW, aSS, aDS, vSS, vDS);
    prep_c<<<1, 256, 0, stream>>>(cskb, aSS, aDS, cv);
    // 3) row score GEMVs
    row_scores<<<BZ * NN, 256, 0, stream>>>(Wh, hx, ho, aSS, aDS, vSS, vDS, cv,
                                            sSrcSS, sDstSS, sSrcDS, sDstDS);
    // 4) softmax -> att
    softmax_att<<<BZ * NN, 256, 0, stream>>>(mx, mo, sSrcSS, sDstSS, sSrcDS, sDstDS, att);
    // 5) out = elu(att @ Wh)
    gemm_nn<<<gridG, 256, 0, stream>>>(att, Wh, out, (size_t)NN * NN, (size_t)NN * FF,
                                       (size_t)NN * FF, NN, FF, 1);
}

// Round 2
// 285.960 us; speedup vs baseline: 5.1547x; 5.1547x over previous
//
#include <hip/hip_runtime.h>
#include <hip/hip_bf16.h>
#include <math.h>

#define BZ 16
#define NN 1024
#define FF 1024
#define ALPHA 0.2f
#define NEG_INF (-9e15f)

typedef __bf16 bf16x8 __attribute__((ext_vector_type(8)));
typedef __bf16 bf16x4 __attribute__((ext_vector_type(4)));
typedef float  f32x4  __attribute__((ext_vector_type(4)));

#define GLOBAL_AS __attribute__((address_space(1)))
#define LDS_AS    __attribute__((address_space(3)))

__device__ inline float waveReduceSum(float v) {
    for (int o = 32; o; o >>= 1) v += __shfl_down(v, o);
    return v;
}
__device__ inline float waveReduceMax(float v) {
    for (int o = 32; o; o >>= 1) v = fmaxf(v, __shfl_down(v, o));
    return v;
}

__device__ inline void load_lds16(const void* g, void* l) {
    __builtin_amdgcn_global_load_lds((const GLOBAL_AS void*)g, (LDS_AS void*)l, 16, 0, 0);
}

// ---------------------------------------------------------------------------
// bf16 MFMA GEMM (m97 structure): C[b] = A[b] @ Bt[b]^T
// A row-major [M][K] bf16, Bt row-major [N][K] bf16, C row-major fp32.
// 128x128 tile, BK=32, 256 threads (4 waves, 2x2), 4x4 16x16x32 frags/wave.
// ---------------------------------------------------------------------------
__global__ __launch_bounds__(256) void gemm_bf16(
    const __bf16* __restrict__ A, const __bf16* __restrict__ Bt, float* __restrict__ C,
    size_t sA, size_t sB, size_t sC, int K, int Ncols, int doElu)
{
    const int b = blockIdx.z;
    const int tileM = blockIdx.y * 128;
    const int tileN = blockIdx.x * 128;
    const __bf16* Ab  = A  + (size_t)b * sA;
    const __bf16* Btb = Bt + (size_t)b * sB;
    float* Cb = C + (size_t)b * sC;

    __shared__ __bf16 As[128 * 32];   // [row][k] linear, 8KB
    __shared__ __bf16 Bs[128 * 32];

    const int tid  = threadIdx.x;
    const int lane = tid & 63;
    const int wid  = tid >> 6;
    const int wm   = (wid >> 1) * 64;   // wave row offset in tile
    const int wn   = (wid & 1) * 64;    // wave col offset

    const int srow = tid >> 2;          // 0..63 staging row
    const int scol = (tid & 3) * 8;     // k element offset

    const __bf16* ga0 = Ab  + (size_t)(tileM + srow) * K + scol;
    const __bf16* ga1 = Ab  + (size_t)(tileM + 64 + srow) * K + scol;
    const __bf16* gb0 = Btb + (size_t)(tileN + srow) * K + scol;
    const __bf16* gb1 = Btb + (size_t)(tileN + 64 + srow) * K + scol;

    f32x4 acc[4][4];
    #pragma unroll
    for (int i = 0; i < 4; ++i)
        #pragma unroll
        for (int j = 0; j < 4; ++j)
            acc[i][j] = (f32x4){0.f, 0.f, 0.f, 0.f};

    const bf16x8* Alds = (const bf16x8*)As;
    const bf16x8* Blds = (const bf16x8*)Bs;

    for (int k0 = 0; k0 < K; k0 += 32) {
        load_lds16(ga0, (char*)As + wid * 1024);
        load_lds16(ga1, (char*)As + 4096 + wid * 1024);
        load_lds16(gb0, (char*)Bs + wid * 1024);
        load_lds16(gb1, (char*)Bs + 4096 + wid * 1024);
        ga0 += 32; ga1 += 32; gb0 += 32; gb1 += 32;
        __syncthreads();   // drains vmcnt -> staged data visible

        bf16x8 av[4], bv[4];
        #pragma unroll
        for (int m = 0; m < 4; ++m)
            av[m] = Alds[(wm + m * 16 + (lane & 15)) * 4 + (lane >> 4)];
        #pragma unroll
        for (int n = 0; n < 4; ++n)
            bv[n] = Blds[(wn + n * 16 + (lane & 15)) * 4 + (lane >> 4)];

        #pragma unroll
        for (int m = 0; m < 4; ++m)
            #pragma unroll
            for (int n = 0; n < 4; ++n)
                acc[m][n] = __builtin_amdgcn_mfma_f32_16x16x32_bf16(
                    av[m], bv[n], acc[m][n], 0, 0, 0);

        __syncthreads();   // reads done before next stage overwrites
    }

    #pragma unroll
    for (int m = 0; m < 4; ++m) {
        const int row0 = tileM + wm + m * 16 + (lane >> 4) * 4;
        #pragma unroll
        for (int n = 0; n < 4; ++n) {
            const int col = tileN + wn + n * 16 + (lane & 15);
            #pragma unroll
            for (int r = 0; r < 4; ++r) {
                float v = acc[m][n][r];
                if (doElu) v = (v > 0.f) ? v : expm1f(v);
                Cb[(size_t)(row0 + r) * Ncols + col] = v;
            }
        }
    }
}

// ---------------------------------------------------------------------------
// Linear fp32 -> bf16 convert, 8 elems/thread.
// ---------------------------------------------------------------------------
__global__ __launch_bounds__(256) void cvt_bf16(
    const float* __restrict__ in, __bf16* __restrict__ out, size_t n8)
{
    size_t t = (size_t)blockIdx.x * 256 + threadIdx.x;
    if (t >= n8) return;
    const float4* i4 = (const float4*)in;
    float4 a = i4[t * 2], b = i4[t * 2 + 1];
    bf16x8 v = { (__bf16)a.x, (__bf16)a.y, (__bf16)a.z, (__bf16)a.w,
                 (__bf16)b.x, (__bf16)b.y, (__bf16)b.z, (__bf16)b.w };
    ((bf16x8*)out)[t] = v;
}

// ---------------------------------------------------------------------------
// Transpose + convert: in [R][C] fp32 (per batch) -> out [C][R] bf16.
// 64x64 tile, 256 threads.
// ---------------------------------------------------------------------------
__global__ __launch_bounds__(256) void transpose_cvt(
    const float* __restrict__ in, __bf16* __restrict__ out, int R, int C)
{
    const int b = blockIdx.z;
    const float* ib = in + (size_t)b * R * C;
    __bf16* ob = out + (size_t)b * R * C;
    const int r0 = blockIdx.y * 64;
    const int c0 = blockIdx.x * 64;

    __shared__ __bf16 t[64][66];

    #pragma unroll
    for (int it = 0; it < 16; ++it) {
        int idx = threadIdx.x + it * 256;
        int r = idx >> 6, c = idx & 63;
        t[r][c] = (__bf16)ib[(size_t)(r0 + r) * C + c0 + c];
    }
    __syncthreads();
    #pragma unroll
    for (int it = 0; it < 4; ++it) {
        int idx = threadIdx.x + it * 256;   // 0..1023
        int rr = idx >> 4;                  // out-row within tile (c-dim)
        int cc = (idx & 15) * 4;            // out-col base (r-dim)
        bf16x4 v = { t[cc][rr], t[cc + 1][rr], t[cc + 2][rr], t[cc + 3][rr] };
        *(bf16x4*)&ob[(size_t)(c0 + rr) * R + r0 + cc] = v;
    }
}

// ---------------------------------------------------------------------------
// v = csk_W^T @ a2 for SS and DS. grid: FF/64 blocks x 256 threads.
// ---------------------------------------------------------------------------
__global__ __launch_bounds__(256) void prep_v(
    const float* __restrict__ cskW, const float* __restrict__ aSS,
    const float* __restrict__ aDS, float* __restrict__ vSS, float* __restrict__ vDS)
{
    const int g0 = blockIdx.x * 64;
    const int gl = threadIdx.x & 63;
    const int fs = threadIdx.x >> 6;   // 0..3
    const int g = g0 + gl;
    float aS = 0.f, aD = 0.f;
    for (int f = fs * 256; f < fs * 256 + 256; ++f) {
        float w = cskW[(size_t)f * FF + g];
        aS += w * aSS[FF + f];
        aD += w * aDS[FF + f];
    }
    __shared__ float rS[4][64], rD[4][64];
    rS[fs][gl] = aS; rD[fs][gl] = aD;
    __syncthreads();
    if (fs == 0) {
        vSS[g] = rS[0][gl] + rS[1][gl] + rS[2][gl] + rS[3][gl];
        vDS[g] = rD[0][gl] + rD[1][gl] + rD[2][gl] + rD[3][gl];
    }
}

// c = csk_b . a2 for SS and DS. 1 block.
__global__ __launch_bounds__(256) void prep_c(
    const float* __restrict__ cskb, const float* __restrict__ aSS,
    const float* __restrict__ aDS, float* __restrict__ cv)
{
    int t = threadIdx.x;
    float cS = 0.f, cD = 0.f;
    for (int f = t; f < FF; f += 256) {
        float bb = cskb[f];
        cS += bb * aSS[FF + f];
        cD += bb * aDS[FF + f];
    }
    cS = waveReduceSum(cS);
    cD = waveReduceSum(cD);
    __shared__ float rA[4], rB[4];
    int wid = t >> 6;
    if ((t & 63) == 0) { rA[wid] = cS; rB[wid] = cD; }
    __syncthreads();
    if (t == 0) {
        cv[0] = rA[0] + rA[1] + rA[2] + rA[3];
        cv[1] = rB[0] + rB[1] + rB[2] + rB[3];
    }
}

// ---------------------------------------------------------------------------
// Per-row score GEMVs (fp32 Wh).
// ---------------------------------------------------------------------------
__global__ __launch_bounds__(256) void row_scores(
    const float* __restrict__ Wh, const float* __restrict__ hx, const float* __restrict__ ho,
    const float* __restrict__ aSS, const float* __restrict__ aDS,
    const float* __restrict__ vSS, const float* __restrict__ vDS,
    const float* __restrict__ cv,
    float* __restrict__ sSrcSS, float* __restrict__ sDstSS,
    float* __restrict__ sSrcDS, float* __restrict__ sDstDS)
{
    const int row = blockIdx.x;   // b*N + i
    const float* whr = Wh + (size_t)row * FF;
    const float* hxr = hx + (size_t)row * FF;
    const float* hor = ho + (size_t)row * FF;
    const int t = threadIdx.x;

    float d0 = 0.f, d1 = 0.f, d2 = 0.f, d3 = 0.f, d4 = 0.f, d5 = 0.f;
    for (int k = t; k < FF; k += 256) {
        float w = whr[k];
        d0 += w * aSS[k];
        d1 += w * aSS[FF + k];
        d2 += w * aDS[k];
        d3 += w * aDS[FF + k];
        d4 += hxr[k] * vSS[k];
        d5 += hor[k] * vDS[k];
    }
    d0 = waveReduceSum(d0); d1 = waveReduceSum(d1); d2 = waveReduceSum(d2);
    d3 = waveReduceSum(d3); d4 = waveReduceSum(d4); d5 = waveReduceSum(d5);

    __shared__ float red[4][6];
    int wid = t >> 6;
    if ((t & 63) == 0) {
        red[wid][0] = d0; red[wid][1] = d1; red[wid][2] = d2;
        red[wid][3] = d3; red[wid][4] = d4; red[wid][5] = d5;
    }
    __syncthreads();
    if (t == 0) {
        float s0 = 0, s1 = 0, s2 = 0, s3 = 0, s4 = 0, s5 = 0;
        for (int w = 0; w < 4; ++w) {
            s0 += red[w][0]; s1 += red[w][1]; s2 += red[w][2];
            s3 += red[w][3]; s4 += red[w][4]; s5 += red[w][5];
        }
        sSrcSS[row] = s0;
        sDstSS[row] = s1 + s4 + cv[0];
        sSrcDS[row] = s2;
        sDstDS[row] = s3 + s5 + cv[1];
    }
}

// ---------------------------------------------------------------------------
// Row softmax -> att (bf16). One block per row; thread owns j = 4t..4t+3.
// ---------------------------------------------------------------------------
__global__ __launch_bounds__(256) void softmax_att(
    const float* __restrict__ mx, const float* __restrict__ mo,
    const float* __restrict__ sSrcSS, const float* __restrict__ sDstSS,
    const float* __restrict__ sSrcDS, const float* __restrict__ sDstDS,
    __bf16* __restrict__ att)
{
    const int row = blockIdx.x;       // b*N + i
    const int base = row & ~(NN - 1); // b*N
    const int t = threadIdx.x;
    const float srcS = sSrcSS[row];
    const float srcD = sSrcDS[row];
    const float4* mxr = (const float4*)(mx + (size_t)row * NN);
    const float4* mor = (const float4*)(mo + (size_t)row * NN);
    const float4* dSp = (const float4*)(sDstSS + base);
    const float4* dDp = (const float4*)(sDstDS + base);

    float4 a = mxr[t], o = mor[t], dS = dSp[t], dD = dDp[t];
    const float* ap = (const float*)&a;
    const float* op = (const float*)&o;
    const float* sp = (const float*)&dS;
    const float* dp = (const float*)&dD;

    float ev[4];
    float m = -INFINITY;
    #pragma unroll
    for (int l = 0; l < 4; ++l) {
        float eS = srcS + sp[l];
        float lS = (eS >= 0.f) ? eS : ALPHA * eS;
        float eD = srcD + dp[l];
        float lD = (eD >= 0.f) ? eD : ALPHA * eD;
        float val = (ap[l] > 0.f) ? (lS * ap[l] + lD * op[l]) : NEG_INF;
        ev[l] = val;
        m = fmaxf(m, val);
    }
    m = waveReduceMax(m);
    __shared__ float redA[4], redB[4];
    int wid = t >> 6;
    if ((t & 63) == 0) redA[wid] = m;
    __syncthreads();
    float bm = fmaxf(fmaxf(redA[0], redA[1]), fmaxf(redA[2], redA[3]));

    float s = 0.f;
    #pragma unroll
    for (int l = 0; l < 4; ++l) {
        float p = expf(ev[l] - bm);
        ev[l] = p;
        s += p;
    }
    s = waveReduceSum(s);
    if ((t & 63) == 0) redB[wid] = s;
    __syncthreads();
    float bs = redB[0] + redB[1] + redB[2] + redB[3];
    float inv = 1.f / bs;

    bf16x4 v = { (__bf16)(ev[0] * inv), (__bf16)(ev[1] * inv),
                 (__bf16)(ev[2] * inv), (__bf16)(ev[3] * inv) };
    *(bf16x4*)&att[(size_t)row * NN + t * 4] = v;
}

// ---------------------------------------------------------------------------
extern "C" void kernel_launch(void* const* d_in, const int* in_sizes, int n_in,
                              void* d_out, int out_size, void* d_ws, size_t ws_size,
                              hipStream_t stream)
{
    const float* h    = (const float*)d_in[0];
    const float* hx   = (const float*)d_in[1];
    const float* ho   = (const float*)d_in[2];
    const float* mx   = (const float*)d_in[3];
    const float* mo   = (const float*)d_in[4];
    const float* W    = (const float*)d_in[5];
    const float* aSS  = (const float*)d_in[6];
    const float* aDS  = (const float*)d_in[7];
    const float* cskW = (const float*)d_in[8];
    const float* cskb = (const float*)d_in[9];
    float* out = (float*)d_out;

    char* ws = (char*)d_ws;
    const size_t MB = 1024 * 1024;
    // region0: 64MB Wh fp32; att_bf (32MB) overlays it once Wh is dead
    float*  Wh     = (float*)ws;
    __bf16* att_bf = (__bf16*)ws;
    // region1: 32MB h_bf; WhT_bf overlays it once h_bf is dead
    __bf16* h_bf   = (__bf16*)(ws + 64 * MB);
    __bf16* WhT_bf = (__bf16*)(ws + 64 * MB);
    // region2: 2MB W^T bf16
    __bf16* WbfT   = (__bf16*)(ws + 96 * MB);
    // region3: small vectors
    float* vSS    = (float*)(ws + 98 * MB);
    float* vDS    = vSS + FF;
    float* cv     = vDS + FF;
    float* sSrcSS = cv + 64;
    float* sDstSS = sSrcSS + BZ * NN;
    float* sSrcDS = sDstSS + BZ * NN;
    float* sDstDS = sSrcDS + BZ * NN;

    const size_t BIG = (size_t)BZ * NN * FF;

    // 1) h -> bf16
    cvt_bf16<<<(BIG / 8 + 255) / 256, 256, 0, stream>>>(h, h_bf, BIG / 8);
    // 2) W -> W^T bf16
    transpose_cvt<<<dim3(16, 16, 1), 256, 0, stream>>>(W, WbfT, FF, FF);
    // 3) Wh = h @ W  (bf16 MFMA, fp32 out)
    gemm_bf16<<<dim3(8, 8, BZ), 256, 0, stream>>>(
        h_bf, WbfT, Wh, (size_t)NN * FF, 0, (size_t)NN * FF, FF, FF, 0);
    // 4) score prep
    prep_v<<<16, 256, 0, stream>>>(cskW, aSS, aDS, vSS, vDS);
    prep_c<<<1, 256, 0, stream>>>(cskb, aSS, aDS, cv);
    // 5) row score GEMVs (reads fp32 Wh)
    row_scores<<<BZ * NN, 256, 0, stream>>>(Wh, hx, ho, aSS, aDS, vSS, vDS, cv,
                                            sSrcSS, sDstSS, sSrcDS, sDstDS);
    // 6) Wh -> Wh^T bf16 (overwrites h_bf region; h_bf dead after step 3)
    transpose_cvt<<<dim3(16, 16, BZ), 256, 0, stream>>>(Wh, WhT_bf, NN, FF);
    // 7) softmax -> att bf16 (overlays Wh region; Wh dead after steps 5,6)
    softmax_att<<<BZ * NN, 256, 0, stream>>>(mx, mo, sSrcSS, sDstSS, sSrcDS, sDstDS,
                                             att_bf);
    // 8) out = elu(att @ Wh)
    gemm_bf16<<<dim3(8, 8, BZ), 256, 0, stream>>>(
        att_bf, WhT_bf, out, (size_t)NN * NN, (size_t)FF * NN, (size_t)NN * FF,
        NN, FF, 1);
}

// Round 3
// 209.426 us; speedup vs baseline: 7.0385x; 1.3654x over previous
//
#include <hip/hip_runtime.h>
#include <hip/hip_bf16.h>
#include <math.h>

#define BZ 16
#define NN 1024
#define FF 1024
#define ALPHA 0.2f
#define NEG_INF (-9e15f)

typedef __bf16 bf16x8 __attribute__((ext_vector_type(8)));
typedef __bf16 bf16x4 __attribute__((ext_vector_type(4)));
typedef float  f32x4  __attribute__((ext_vector_type(4)));

#define GLOBAL_AS __attribute__((address_space(1)))
#define LDS_AS    __attribute__((address_space(3)))

__device__ inline void load_lds16(const void* g, void* l) {
    __builtin_amdgcn_global_load_lds((const GLOBAL_AS void*)g, (LDS_AS void*)l, 16, 0, 0);
}

__device__ inline float waveReduceSum(float v) {
    for (int o = 32; o; o >>= 1) v += __shfl_down(v, o);
    return v;
}
__device__ inline float waveReduceMax(float v) {
    for (int o = 32; o; o >>= 1) v = fmaxf(v, __shfl_down(v, o));
    return v;
}

// ===========================================================================
// 256x256 8-phase bf16 MFMA GEMM (m201/T2+T3+T4+T5 structure, plain HIP).
// C = A @ Bt^T.  A [M=16384][K=1024] bf16 row-major; Bt [1024][K] bf16
// row-major (per-1024-row batch stride sB; 0 = shared).
// BK=64, 8 waves (2x4), 512 thr, 128KB LDS (2 dbuf x (A 32K + B 32K)).
// EPI==1: fp32 + elu, row-major.  EPI==2: bf16 transposed per batch (C^T).
// ===========================================================================
template<int EPI>
__global__ __launch_bounds__(512, 2) void gemm256(
    const __bf16* __restrict__ A, const __bf16* __restrict__ Bt,
    float* __restrict__ Cf, __bf16* __restrict__ Ct, size_t sB)
{
    __shared__ char lds[131072];

    // bijective XCD swizzle (nwg = 256, divisible by 8)
    const int bid = blockIdx.x;
    const int l   = (bid & 7) * 32 + (bid >> 3);
    const int tileM = (l >> 2) * 256;          // 64 M-tiles
    const int tileN = (l & 3) * 256;           // 4 N-tiles

    const int tid = threadIdx.x, lane = tid & 63, wid = tid >> 6;
    const int wr = wid >> 2, wc = wid & 3;     // 2 x 4 waves

    const int batch = tileM >> 10;
    const char* Ab  = (const char*)(A + (size_t)tileM * FF);
    const char* Bbp = (const char*)(Bt + (size_t)batch * sB + (size_t)tileN * FF);

    // --- staging map: thread -> 2x16B slots of a 16KB half-tile (linear LDS,
    //     inverse-swizzled global source; rule #21) ---
    const int o1 = wid * 1024 + lane * 16;     // [0, 8192)
    const int o2 = o1 + 8192;                  // [8192, 16384)
    const int r1 = o1 >> 7, r2 = o2 >> 7;      // row in 128-row half
    const size_t raoff1 = (size_t)r1 * 2048 + ((o1 & 127) ^ ((r1 & 7) << 4));
    const size_t raoff2 = (size_t)r2 * 2048 + ((o2 & 127) ^ ((r2 & 7) << 4));

#define STAGE(gb, ldsoff, half, kt) do {                                        \
    const char* g_ = (gb) + (size_t)(half) * (128 * 2048) + (size_t)(kt) * 128; \
    load_lds16(g_ + raoff1, lds + (ldsoff) + (half) * 16384 + wid * 1024);      \
    load_lds16(g_ + raoff2, lds + (ldsoff) + (half) * 16384 + 8192 + wid * 1024);\
} while (0)

    // --- fragment read addressing (swizzled) ---
    const int fr = lane & 15, kq = lane >> 4;
    const int fswz = (fr & 7) << 4;
    const int ck0 = (kq * 16) ^ fswz;          // K-half 0
    const int ck1 = (64 + kq * 16) ^ fswz;     // K-half 1
    const int abase = (wr * 128 + fr) * 128;
    const int bbase = 32768 + (wc * 64 + fr) * 128;

#define RD(off) (*(const bf16x8*)(lds + (off)))
#define DSA(P, f0) do { _Pragma("unroll") for (int m = 0; m < 4; ++m) {      \
    av[m][0] = RD((P) * 65536 + abase + (f0 + m) * 2048 + ck0);              \
    av[m][1] = RD((P) * 65536 + abase + (f0 + m) * 2048 + ck1); } } while (0)
#define DSB(P, f0, bv_) do { _Pragma("unroll") for (int n = 0; n < 2; ++n) { \
    bv_[n][0] = RD((P) * 65536 + bbase + (f0 + n) * 2048 + ck0);             \
    bv_[n][1] = RD((P) * 65536 + bbase + (f0 + n) * 2048 + ck1); } } while (0)
#define MFMAQ(m0, bv_, n0) do {                                              \
    _Pragma("unroll") for (int m = 0; m < 4; ++m)                            \
    _Pragma("unroll") for (int n = 0; n < 2; ++n) {                          \
        acc[m0 + m][n0 + n] = __builtin_amdgcn_mfma_f32_16x16x32_bf16(       \
            av[m][0], bv_[n][0], acc[m0 + m][n0 + n], 0, 0, 0);              \
        acc[m0 + m][n0 + n] = __builtin_amdgcn_mfma_f32_16x16x32_bf16(       \
            av[m][1], bv_[n][1], acc[m0 + m][n0 + n], 0, 0, 0); } } while (0)
#define BAR   __builtin_amdgcn_s_barrier()
#define LGKM0 do { asm volatile("s_waitcnt lgkmcnt(0)" ::: "memory");        \
                   __builtin_amdgcn_sched_barrier(0); } while (0)
#define VM4   asm volatile("s_waitcnt vmcnt(4)" ::: "memory")
#define VM0   asm volatile("s_waitcnt vmcnt(0)" ::: "memory")
#define PRIO1 __builtin_amdgcn_s_setprio(1)
#define PRIO0 __builtin_amdgcn_s_setprio(0)

    f32x4 acc[8][4];
    #pragma unroll
    for (int m = 0; m < 8; ++m)
        #pragma unroll
        for (int n = 0; n < 4; ++n) acc[m][n] = (f32x4){0.f, 0.f, 0.f, 0.f};

    bf16x8 av[4][2], bvL[2][2], bvH[2][2];

    // ---- prologue: K-tile 0 (4 halves) + t1:{B-lo, A-lo} in flight ----
    STAGE(Ab,      0, 0, 0);  STAGE(Ab,      0, 1, 0);
    STAGE(Bbp, 32768, 0, 0);  STAGE(Bbp, 32768, 1, 0);
    STAGE(Bbp, 65536 + 32768, 0, 1);
    STAGE(Ab,  65536,         0, 1);
    VM4; BAR;   // K-tile 0 fully staged; 2 half-tiles of t1 in flight

    const int NT = FF / 64;   // 16
    for (int it = 0; it < NT / 2; ++it) {
        const int t   = 2 * it;
        const int kt1 = t + 1;
        const int kt2 = (t + 2 < NT) ? t + 2 : NT - 1;   // clamped tail
        const int kt3 = (t + 3 < NT) ? t + 3 : NT - 1;

        // ph1: tile t (buf0): A frags 0-3 + B frags 0-1 | stage A-hi(t+1)
        DSA(0, 0); DSB(0, 0, bvL);
        STAGE(Ab, 65536, 1, kt1);
        BAR; LGKM0; PRIO1; MFMAQ(0, bvL, 0); PRIO0; BAR;
        // ph2: B frags 2-3 | stage B-hi(t+1)
        DSB(0, 2, bvH);
        STAGE(Bbp, 65536 + 32768, 1, kt1);
        BAR; LGKM0; PRIO1; MFMAQ(0, bvH, 2); PRIO0; BAR;
        // ph3: A frags 4-7 | stage B-lo(t+2) into buf0 (B reads done ph2)
        DSA(0, 4);
        STAGE(Bbp, 32768, 0, kt2);
        BAR; LGKM0; PRIO1; MFMAQ(4, bvL, 0); PRIO0; BAR;
        // ph4: no ds reads | stage A-lo(t+2) (A reads done ph3) | vmcnt
        STAGE(Ab, 0, 0, kt2);
        BAR; PRIO1; MFMAQ(4, bvH, 2); PRIO0; VM4; BAR;

        // ph5: tile t+1 (buf1) | stage A-hi(t+2)
        DSA(1, 0); DSB(1, 0, bvL);
        STAGE(Ab, 0, 1, kt2);
        BAR; LGKM0; PRIO1; MFMAQ(0, bvL, 0); PRIO0; BAR;
        // ph6 | stage B-hi(t+2)
        DSB(1, 2, bvH);
        STAGE(Bbp, 32768, 1, kt2);
        BAR; LGKM0; PRIO1; MFMAQ(0, bvH, 2); PRIO0; BAR;
        // ph7 | stage B-lo(t+3) into buf1 (buf1 B reads done ph6)
        DSA(1, 4);
        STAGE(Bbp, 65536 + 32768, 0, kt3);
        BAR; LGKM0; PRIO1; MFMAQ(4, bvL, 0); PRIO0; BAR;
        // ph8 | stage A-lo(t+3) (buf1 A reads done ph7) | vmcnt
        STAGE(Ab, 65536, 0, kt3);
        BAR; PRIO1; MFMAQ(4, bvH, 2); PRIO0; VM4; BAR;
    }

    // ---- epilogue ----
    if (EPI == 1) {
        #pragma unroll
        for (int fm = 0; fm < 8; ++fm) {
            const int row0 = tileM + wr * 128 + fm * 16 + kq * 4;
            #pragma unroll
            for (int fn = 0; fn < 4; ++fn) {
                const int col = tileN + wc * 64 + fn * 16 + fr;
                #pragma unroll
                for (int r = 0; r < 4; ++r) {
                    float v = acc[fm][fn][r];
                    v = (v > 0.f) ? v : expm1f(v);
                    Cf[(size_t)(row0 + r) * FF + col] = v;
                }
            }
        }
    } else {
        // write C^T bf16 per batch: stage per-wave 128x64 tile into LDS
        VM0; BAR;   // drain tail gloads; all LDS reads finished
        char* wlds = lds + wid * 16384;   // [64 c][128 r] bf16, swizzled
        #pragma unroll
        for (int fm = 0; fm < 8; ++fm)
            #pragma unroll
            for (int fn = 0; fn < 4; ++fn) {
                const int ccol = fn * 16 + fr;
                const int crow = fm * 16 + kq * 4;
                int addr = (ccol * 256 + crow * 2) ^ ((ccol & 7) << 4);
                bf16x4 v = { (__bf16)acc[fm][fn][0], (__bf16)acc[fm][fn][1],
                             (__bf16)acc[fm][fn][2], (__bf16)acc[fm][fn][3] };
                *(bf16x4*)(wlds + addr) = v;
            }
        const int jb = (tileM & 1023) + wr * 128;
        __bf16* Wt = Ct + (size_t)batch * (1024 * 1024);
        #pragma unroll
        for (int pass = 0; pass < 16; ++pass) {
            const int fl  = pass * 4 + (lane >> 4);   // 0..63 (c-dim)
            const int jby = (lane & 15) * 16;         // byte offset in j-dim
            int addr = (fl * 256 + jby) ^ ((fl & 7) << 4);
            bf16x8 v = *(const bf16x8*)(wlds + addr);
            const int fg = tileN + wc * 64 + fl;
            *(bf16x8*)((char*)(Wt + (size_t)fg * 1024 + jb) + jby) = v;
        }
    }
#undef STAGE
#undef RD
#undef DSA
#undef DSB
#undef MFMAQ
}

// ---------------------------------------------------------------------------
__global__ __launch_bounds__(256) void cvt_bf16(
    const float* __restrict__ in, __bf16* __restrict__ out, size_t n8)
{
    size_t t = (size_t)blockIdx.x * 256 + threadIdx.x;
    if (t >= n8) return;
    const float4* i4 = (const float4*)in;
    float4 a = i4[t * 2], b = i4[t * 2 + 1];
    bf16x8 v = { (__bf16)a.x, (__bf16)a.y, (__bf16)a.z, (__bf16)a.w,
                 (__bf16)b.x, (__bf16)b.y, (__bf16)b.z, (__bf16)b.w };
    ((bf16x8*)out)[t] = v;
}

// Transpose + convert: in [R][C] fp32 -> out [C][R] bf16 (used for W only).
__global__ __launch_bounds__(256) void transpose_cvt(
    const float* __restrict__ in, __bf16* __restrict__ out, int R, int C)
{
    const float* ib = in;
    __bf16* ob = out;
    const int r0 = blockIdx.y * 64;
    const int c0 = blockIdx.x * 64;
    __shared__ __bf16 t[64][66];
    #pragma unroll
    for (int it = 0; it < 16; ++it) {
        int idx = threadIdx.x + it * 256;
        int r = idx >> 6, c = idx & 63;
        t[r][c] = (__bf16)ib[(size_t)(r0 + r) * C + c0 + c];
    }
    __syncthreads();
    #pragma unroll
    for (int it = 0; it < 4; ++it) {
        int idx = threadIdx.x + it * 256;
        int rr = idx >> 4;
        int cc = (idx & 15) * 4;
        bf16x4 v = { t[cc][rr], t[cc + 1][rr], t[cc + 2][rr], t[cc + 3][rr] };
        *(bf16x4*)&ob[(size_t)(c0 + rr) * R + r0 + cc] = v;
    }
}

// wa[q][i], q in {a1SS, a2SS, a1DS, a2DS}: wa_q = W @ a_q  (row dots).
__global__ __launch_bounds__(256) void prep_wa(
    const float* __restrict__ W, const float* __restrict__ aSS,
    const float* __restrict__ aDS, float* __restrict__ wa)
{
    const int i = blockIdx.x;
    const int t = threadIdx.x;
    float4 w  = ((const float4*)(W + (size_t)i * FF))[t];
    float4 s1 = ((const float4*)aSS)[t];
    float4 s2 = ((const float4*)(aSS + FF))[t];
    float4 d1 = ((const float4*)aDS)[t];
    float4 d2 = ((const float4*)(aDS + FF))[t];
    float v0 = w.x * s1.x + w.y * s1.y + w.z * s1.z + w.w * s1.w;
    float v1 = w.x * s2.x + w.y * s2.y + w.z * s2.z + w.w * s2.w;
    float v2 = w.x * d1.x + w.y * d1.y + w.z * d1.z + w.w * d1.w;
    float v3 = w.x * d2.x + w.y * d2.y + w.z * d2.z + w.w * d2.w;
    v0 = waveReduceSum(v0); v1 = waveReduceSum(v1);
    v2 = waveReduceSum(v2); v3 = waveReduceSum(v3);
    __shared__ float red[4][4];
    int wid = t >> 6;
    if ((t & 63) == 0) { red[wid][0] = v0; red[wid][1] = v1; red[wid][2] = v2; red[wid][3] = v3; }
    __syncthreads();
    if (t < 4) {
        float s = red[0][t] + red[1][t] + red[2][t] + red[3][t];
        wa[(size_t)t * FF + i] = s;
    }
}

// v = csk_W^T @ a2 for SS and DS.
__global__ __launch_bounds__(256) void prep_v(
    const float* __restrict__ cskW, const float* __restrict__ aSS,
    const float* __restrict__ aDS, float* __restrict__ vSS, float* __restrict__ vDS)
{
    const int g0 = blockIdx.x * 64;
    const int gl = threadIdx.x & 63;
    const int fs = threadIdx.x >> 6;
    const int g = g0 + gl;
    float aS = 0.f, aD = 0.f;
    for (int f = fs * 256; f < fs * 256 + 256; ++f) {
        float w = cskW[(size_t)f * FF + g];
        aS += w * aSS[FF + f];
        aD += w * aDS[FF + f];
    }
    __shared__ float rS[4][64], rD[4][64];
    rS[fs][gl] = aS; rD[fs][gl] = aD;
    __syncthreads();
    if (fs == 0) {
        vSS[g] = rS[0][gl] + rS[1][gl] + rS[2][gl] + rS[3][gl];
        vDS[g] = rD[0][gl] + rD[1][gl] + rD[2][gl] + rD[3][gl];
    }
}

__global__ __launch_bounds__(256) void prep_c(
    const float* __restrict__ cskb, const float* __restrict__ aSS,
    const float* __restrict__ aDS, float* __restrict__ cv)
{
    int t = threadIdx.x;
    float cS = 0.f, cD = 0.f;
    for (int f = t; f < FF; f += 256) {
        float bb = cskb[f];
        cS += bb * aSS[FF + f];
        cD += bb * aDS[FF + f];
    }
    cS = waveReduceSum(cS);
    cD = waveReduceSum(cD);
    __shared__ float rA[4], rB[4];
    int wid = t >> 6;
    if ((t & 63) == 0) { rA[wid] = cS; rB[wid] = cD; }
    __syncthreads();
    if (t == 0) {
        cv[0] = rA[0] + rA[1] + rA[2] + rA[3];
        cv[1] = rB[0] + rB[1] + rB[2] + rB[3];
    }
}

// Row scores from h/hx/ho directly (fp32):
// sSrc = h.wa1 ; sDst = h.wa2 + hreact.v + c
__global__ __launch_bounds__(256) void row_scores2(
    const float* __restrict__ h, const float* __restrict__ hx, const float* __restrict__ ho,
    const float* __restrict__ wa, const float* __restrict__ vSS, const float* __restrict__ vDS,
    const float* __restrict__ cv,
    float* __restrict__ sSrcSS, float* __restrict__ sDstSS,
    float* __restrict__ sSrcDS, float* __restrict__ sDstDS)
{
    const int row = blockIdx.x;
    const int t = threadIdx.x;
    float4 hv = ((const float4*)(h  + (size_t)row * FF))[t];
    float4 xv = ((const float4*)(hx + (size_t)row * FF))[t];
    float4 ov = ((const float4*)(ho + (size_t)row * FF))[t];
    float4 w0 = ((const float4*)wa)[t];
    float4 w1 = ((const float4*)(wa + FF))[t];
    float4 w2 = ((const float4*)(wa + 2 * FF))[t];
    float4 w3 = ((const float4*)(wa + 3 * FF))[t];
    float4 vs = ((const float4*)vSS)[t];
    float4 vd = ((const float4*)vDS)[t];
    float d0 = hv.x * w0.x + hv.y * w0.y + hv.z * w0.z + hv.w * w0.w;
    float d1 = hv.x * w1.x + hv.y * w1.y + hv.z * w1.z + hv.w * w1.w;
    float d2 = hv.x * w2.x + hv.y * w2.y + hv.z * w2.z + hv.w * w2.w;
    float d3 = hv.x * w3.x + hv.y * w3.y + hv.z * w3.z + hv.w * w3.w;
    float d4 = xv.x * vs.x + xv.y * vs.y + xv.z * vs.z + xv.w * vs.w;
    float d5 = ov.x * vd.x + ov.y * vd.y + ov.z * vd.z + ov.w * vd.w;
    d0 = waveReduceSum(d0); d1 = waveReduceSum(d1); d2 = waveReduceSum(d2);
    d3 = waveReduceSum(d3); d4 = waveReduceSum(d4); d5 = waveReduceSum(d5);
    __shared__ float red[4][6];
    int wid = t >> 6;
    if ((t & 63) == 0) {
        red[wid][0] = d0; red[wid][1] = d1; red[wid][2] = d2;
        red[wid][3] = d3; red[wid][4] = d4; red[wid][5] = d5;
    }
    __syncthreads();
    if (t == 0) {
        float s0 = 0, s1 = 0, s2 = 0, s3 = 0, s4 = 0, s5 = 0;
        for (int w = 0; w < 4; ++w) {
            s0 += red[w][0]; s1 += red[w][1]; s2 += red[w][2];
            s3 += red[w][3]; s4 += red[w][4]; s5 += red[w][5];
        }
        sSrcSS[row] = s0;
        sDstSS[row] = s1 + s4 + cv[0];
        sSrcDS[row] = s2;
        sDstDS[row] = s3 + s5 + cv[1];
    }
}

// Row softmax -> att (bf16).
__global__ __launch_bounds__(256) void softmax_att(
    const float* __restrict__ mx, const float* __restrict__ mo,
    const float* __restrict__ sSrcSS, const float* __restrict__ sDstSS,
    const float* __restrict__ sSrcDS, const float* __restrict__ sDstDS,
    __bf16* __restrict__ att)
{
    const int row = blockIdx.x;
    const int base = row & ~(NN - 1);
    const int t = threadIdx.x;
    const float srcS = sSrcSS[row];
    const float srcD = sSrcDS[row];
    const float4* mxr = (const float4*)(mx + (size_t)row * NN);
    const float4* mor = (const float4*)(mo + (size_t)row * NN);
    const float4* dSp = (const float4*)(sDstSS + base);
    const float4* dDp = (const float4*)(sDstDS + base);

    float4 a = mxr[t], o = mor[t], dS = dSp[t], dD = dDp[t];
    const float* ap = (const float*)&a;
    const float* op = (const float*)&o;
    const float* sp = (const float*)&dS;
    const float* dp = (const float*)&dD;

    float ev[4];
    float m = -INFINITY;
    #pragma unroll
    for (int l = 0; l < 4; ++l) {
        float eS = srcS + sp[l];
        float lS = (eS >= 0.f) ? eS : ALPHA * eS;
        float eD = srcD + dp[l];
        float lD = (eD >= 0.f) ? eD : ALPHA * eD;
        float val = (ap[l] > 0.f) ? (lS * ap[l] + lD * op[l]) : NEG_INF;
        ev[l] = val;
        m = fmaxf(m, val);
    }
    m = waveReduceMax(m);
    __shared__ float redA[4], redB[4];
    int wid = t >> 6;
    if ((t & 63) == 0) redA[wid] = m;
    __syncthreads();
    float bm = fmaxf(fmaxf(redA[0], redA[1]), fmaxf(redA[2], redA[3]));

    float s = 0.f;
    #pragma unroll
    for (int l = 0; l < 4; ++l) {
        float p = expf(ev[l] - bm);
        ev[l] = p;
        s += p;
    }
    s = waveReduceSum(s);
    if ((t & 63) == 0) redB[wid] = s;
    __syncthreads();
    float bs = redB[0] + redB[1] + redB[2] + redB[3];
    float inv = 1.f / bs;

    bf16x4 v = { (__bf16)(ev[0] * inv), (__bf16)(ev[1] * inv),
                 (__bf16)(ev[2] * inv), (__bf16)(ev[3] * inv) };
    *(bf16x4*)&att[(size_t)row * NN + t * 4] = v;
}

// ---------------------------------------------------------------------------
extern "C" void kernel_launch(void* const* d_in, const int* in_sizes, int n_in,
                              void* d_out, int out_size, void* d_ws, size_t ws_size,
                              hipStream_t stream)
{
    const float* h    = (const float*)d_in[0];
    const float* hx   = (const float*)d_in[1];
    const float* ho   = (const float*)d_in[2];
    const float* mx   = (const float*)d_in[3];
    const float* mo   = (const float*)d_in[4];
    const float* W    = (const float*)d_in[5];
    const float* aSS  = (const float*)d_in[6];
    const float* aDS  = (const float*)d_in[7];
    const float* cskW = (const float*)d_in[8];
    const float* cskb = (const float*)d_in[9];
    float* out = (float*)d_out;

    char* ws = (char*)d_ws;
    const size_t MB = 1024 * 1024;
    __bf16* h_bf   = (__bf16*)ws;              // 32MB
    __bf16* WhT_bf = (__bf16*)(ws + 32 * MB);  // 32MB (per-batch [F][N] bf16)
    __bf16* att_bf = (__bf16*)(ws + 64 * MB);  // 32MB
    __bf16* WbfT   = (__bf16*)(ws + 96 * MB);  // 2MB
    float* wa     = (float*)(ws + 98 * MB);    // 16KB [4][FF]
    float* vSS    = wa + 4 * FF;
    float* vDS    = vSS + FF;
    float* cv     = vDS + FF;
    float* sSrcSS = cv + 64;
    float* sDstSS = sSrcSS + BZ * NN;
    float* sSrcDS = sDstSS + BZ * NN;
    float* sDstDS = sSrcDS + BZ * NN;

    const size_t BIG = (size_t)BZ * NN * FF;

    // 1) h -> bf16
    cvt_bf16<<<(int)((BIG / 8 + 255) / 256), 256, 0, stream>>>(h, h_bf, BIG / 8);
    // 2) W -> W^T bf16
    transpose_cvt<<<dim3(16, 16, 1), 256, 0, stream>>>(W, WbfT, FF, FF);
    // 3) score prep (fp32, independent of GEMM)
    prep_wa<<<FF, 256, 0, stream>>>(W, aSS, aDS, wa);
    prep_v<<<16, 256, 0, stream>>>(cskW, aSS, aDS, vSS, vDS);
    prep_c<<<1, 256, 0, stream>>>(cskb, aSS, aDS, cv);
    // 4) row scores from h/hx/ho (never touches Wh)
    row_scores2<<<BZ * NN, 256, 0, stream>>>(h, hx, ho, wa, vSS, vDS, cv,
                                             sSrcSS, sDstSS, sSrcDS, sDstDS);
    // 5) Wh^T bf16 = (h @ W)^T  per batch, via 8-phase GEMM with C^T epilogue
    gemm256<2><<<256, 512, 0, stream>>>(h_bf, WbfT, nullptr, WhT_bf, 0);
    // 6) softmax -> att bf16
    softmax_att<<<BZ * NN, 256, 0, stream>>>(mx, mo, sSrcSS, sDstSS, sSrcDS, sDstDS,
                                             att_bf);
    // 7) out = elu(att @ Wh)
    gemm256<1><<<256, 512, 0, stream>>>(att_bf, WhT_bf, out, nullptr,
                                        (size_t)NN * FF);
}

// Round 4
// 203.705 us; speedup vs baseline: 7.2362x; 1.0281x over previous
//
#include <hip/hip_runtime.h>
#include <hip/hip_bf16.h>
#include <math.h>

#define BZ 16
#define NN 1024
#define FF 1024
#define ALPHA 0.2f
#define NEG_INF (-9e15f)

typedef __bf16 bf16x8 __attribute__((ext_vector_type(8)));
typedef __bf16 bf16x4 __attribute__((ext_vector_type(4)));
typedef float  f32x4  __attribute__((ext_vector_type(4)));

#define GLOBAL_AS __attribute__((address_space(1)))
#define LDS_AS    __attribute__((address_space(3)))

__device__ inline void load_lds16(const void* g, void* l) {
    __builtin_amdgcn_global_load_lds((const GLOBAL_AS void*)g, (LDS_AS void*)l, 16, 0, 0);
}

__device__ inline float waveReduceSum(float v) {
    for (int o = 32; o; o >>= 1) v += __shfl_down(v, o);
    return v;
}
__device__ inline float waveReduceMax(float v) {
    for (int o = 32; o; o >>= 1) v = fmaxf(v, __shfl_down(v, o));
    return v;
}

// ===========================================================================
// 256x256 8-phase bf16 MFMA GEMM. C = A @ Bt^T.
// A [M=16384][K=1024] bf16 row-major; Bt [1024][K] bf16 row-major
// (per-1024-row batch stride sB; 0 = shared).
// BK=64, 8 waves (2x4), 512 thr, 128KB LDS (2 dbuf x (A 32K + B 32K)).
// Phase split by K-half: each 16-MFMA cluster is fully independent (16
// distinct accumulators); ds_reads balanced 8/8/8/0 per tile.
// EPI==1: fp32 + elu, row-major.  EPI==2: bf16 transposed per batch (C^T).
// ===========================================================================
template<int EPI>
__global__ __launch_bounds__(512, 2) void gemm256(
    const __bf16* __restrict__ A, const __bf16* __restrict__ Bt,
    float* __restrict__ Cf, __bf16* __restrict__ Ct, size_t sB)
{
    __shared__ char lds[131072];

    // bijective XCD swizzle (nwg = 256, divisible by 8)
    const int bid = blockIdx.x;
    const int l   = (bid & 7) * 32 + (bid >> 3);
    const int tileM = (l >> 2) * 256;          // 64 M-tiles
    const int tileN = (l & 3) * 256;           // 4 N-tiles

    const int tid = threadIdx.x, lane = tid & 63, wid = tid >> 6;
    const int wr = wid >> 2, wc = wid & 3;     // 2 x 4 waves

    const int batch = tileM >> 10;
    const char* Ab  = (const char*)(A + (size_t)tileM * FF);
    const char* Bbp = (const char*)(Bt + (size_t)batch * sB + (size_t)tileN * FF);

    // --- staging map: thread -> 2x16B slots of a 16KB half-tile (linear LDS,
    //     inverse-swizzled global source; rule #21) ---
    const int o1 = wid * 1024 + lane * 16;     // [0, 8192)
    const int o2 = o1 + 8192;                  // [8192, 16384)
    const int r1 = o1 >> 7, r2 = o2 >> 7;      // row in 128-row half
    const size_t raoff1 = (size_t)r1 * 2048 + ((o1 & 127) ^ ((r1 & 7) << 4));
    const size_t raoff2 = (size_t)r2 * 2048 + ((o2 & 127) ^ ((r2 & 7) << 4));

#define STAGE(gb, ldsoff, half, kt) do {                                        \
    const char* g_ = (gb) + (size_t)(half) * (128 * 2048) + (size_t)(kt) * 128; \
    load_lds16(g_ + raoff1, lds + (ldsoff) + (half) * 16384 + wid * 1024);      \
    load_lds16(g_ + raoff2, lds + (ldsoff) + (half) * 16384 + 8192 + wid * 1024);\
} while (0)

    // --- fragment read addressing (swizzled) ---
    const int fr = lane & 15, kq = lane >> 4;
    const int fswz = (fr & 7) << 4;
    const int ck[2] = { (kq * 16) ^ fswz, (64 + kq * 16) ^ fswz };
    const int abase = (wr * 128 + fr) * 128;
    const int bbase = 32768 + (wc * 64 + fr) * 128;

#define RD(off) (*(const bf16x8*)(lds + (off)))
#define RDA(P, m, kh) RD((P) * 65536 + abase + (m) * 2048 + ck[kh])
#define RDB(P, n, kh) RD((P) * 65536 + bbase + (n) * 2048 + ck[kh])
#define MF16(amr, bvr, m0) do {                                              \
    _Pragma("unroll") for (int n = 0; n < 4; ++n)                            \
    _Pragma("unroll") for (int m = 0; m < 4; ++m)                            \
        acc[m0 + m][n] = __builtin_amdgcn_mfma_f32_16x16x32_bf16(            \
            amr[m], bvr[n], acc[m0 + m][n], 0, 0, 0); } while (0)
#define BAR   __builtin_amdgcn_s_barrier()
#define LGKM0 do { asm volatile("s_waitcnt lgkmcnt(0)" ::: "memory");        \
                   __builtin_amdgcn_sched_barrier(0); } while (0)
#define VM4   asm volatile("s_waitcnt vmcnt(4)" ::: "memory")
#define VM0   asm volatile("s_waitcnt vmcnt(0)" ::: "memory")
#define PRIO1 __builtin_amdgcn_s_setprio(1)
#define PRIO0 __builtin_amdgcn_s_setprio(0)

    f32x4 acc[8][4];
    #pragma unroll
    for (int m = 0; m < 8; ++m)
        #pragma unroll
        for (int n = 0; n < 4; ++n) acc[m][n] = (f32x4){0.f, 0.f, 0.f, 0.f};

    bf16x8 a0[4], a47k0[4], a47k1[4], b0[4], b1[4];

    // ---- prologue: K-tile 0 (4 halves) + t1:{B-lo, A-lo} in flight ----
    STAGE(Ab,      0, 0, 0);  STAGE(Ab,      0, 1, 0);
    STAGE(Bbp, 32768, 0, 0);  STAGE(Bbp, 32768, 1, 0);
    STAGE(Bbp, 65536 + 32768, 0, 1);
    STAGE(Ab,  65536,         0, 1);
    VM4; BAR;   // K-tile 0 fully staged; 2 half-tiles of t1 in flight

    const int NT = FF / 64;   // 16
    for (int it = 0; it < NT / 2; ++it) {
        const int t   = 2 * it;
        const int kt1 = t + 1;
        const int kt2 = (t + 2 < NT) ? t + 2 : NT - 1;   // clamped tail
        const int kt3 = (t + 3 < NT) ? t + 3 : NT - 1;

        // ===== tile t (buf0) =====
        // ph1: A0-3 k0 + B k0 | stage A-hi(t+1)
        #pragma unroll
        for (int m = 0; m < 4; ++m) a0[m] = RDA(0, m, 0);
        #pragma unroll
        for (int n = 0; n < 4; ++n) b0[n] = RDB(0, n, 0);
        STAGE(Ab, 65536, 1, kt1);
        BAR; LGKM0; PRIO1; MF16(a0, b0, 0); PRIO0; BAR;
        // ph2: A0-3 k1 + B k1 | stage B-hi(t+1)
        #pragma unroll
        for (int m = 0; m < 4; ++m) a0[m] = RDA(0, m, 1);
        #pragma unroll
        for (int n = 0; n < 4; ++n) b1[n] = RDB(0, n, 1);
        STAGE(Bbp, 65536 + 32768, 1, kt1);
        BAR; LGKM0; PRIO1; MF16(a0, b1, 0); PRIO0; BAR;
        // ph3: A4-7 both k | stage B-lo(t+2) into buf0 (B reads done ph2)
        #pragma unroll
        for (int m = 0; m < 4; ++m) { a47k0[m] = RDA(0, 4 + m, 0); a47k1[m] = RDA(0, 4 + m, 1); }
        STAGE(Bbp, 32768, 0, kt2);
        BAR; LGKM0; PRIO1; MF16(a47k0, b0, 4); PRIO0; BAR;
        // ph4: no reads | stage A-lo(t+2) into buf0 (A reads done ph3) | vmcnt
        STAGE(Ab, 0, 0, kt2);
        BAR; PRIO1; MF16(a47k1, b1, 4); PRIO0; VM4; BAR;

        // ===== tile t+1 (buf1) =====
        // ph5 | stage A-hi(t+2)
        #pragma unroll
        for (int m = 0; m < 4; ++m) a0[m] = RDA(1, m, 0);
        #pragma unroll
        for (int n = 0; n < 4; ++n) b0[n] = RDB(1, n, 0);
        STAGE(Ab, 0, 1, kt2);
        BAR; LGKM0; PRIO1; MF16(a0, b0, 0); PRIO0; BAR;
        // ph6 | stage B-hi(t+2)
        #pragma unroll
        for (int m = 0; m < 4; ++m) a0[m] = RDA(1, m, 1);
        #pragma unroll
        for (int n = 0; n < 4; ++n) b1[n] = RDB(1, n, 1);
        STAGE(Bbp, 32768, 1, kt2);
        BAR; LGKM0; PRIO1; MF16(a0, b1, 0); PRIO0; BAR;
        // ph7 | stage B-lo(t+3) into buf1 (buf1 B reads done ph6)
        #pragma unroll
        for (int m = 0; m < 4; ++m) { a47k0[m] = RDA(1, 4 + m, 0); a47k1[m] = RDA(1, 4 + m, 1); }
        STAGE(Bbp, 65536 + 32768, 0, kt3);
        BAR; LGKM0; PRIO1; MF16(a47k0, b0, 4); PRIO0; BAR;
        // ph8 | stage A-lo(t+3) into buf1 (buf1 A reads done ph7) | vmcnt
        STAGE(Ab, 65536, 0, kt3);
        BAR; PRIO1; MF16(a47k1, b1, 4); PRIO0; VM4; BAR;
    }

    // ---- epilogue ----
    if (EPI == 1) {
        #pragma unroll
        for (int fm = 0; fm < 8; ++fm) {
            const int row0 = tileM + wr * 128 + fm * 16 + kq * 4;
            #pragma unroll
            for (int fn = 0; fn < 4; ++fn) {
                const int col = tileN + wc * 64 + fn * 16 + fr;
                #pragma unroll
                for (int r = 0; r < 4; ++r) {
                    float v = acc[fm][fn][r];
                    v = (v > 0.f) ? v : expm1f(v);
                    Cf[(size_t)(row0 + r) * FF + col] = v;
                }
            }
        }
    } else {
        // write C^T bf16 per batch: stage per-wave 128x64 tile into LDS
        VM0; BAR;   // drain tail gloads; all LDS reads finished
        char* wlds = lds + wid * 16384;   // [64 c][128 r] bf16, swizzled
        #pragma unroll
        for (int fm = 0; fm < 8; ++fm)
            #pragma unroll
            for (int fn = 0; fn < 4; ++fn) {
                const int ccol = fn * 16 + fr;
                const int crow = fm * 16 + kq * 4;
                int addr = (ccol * 256 + crow * 2) ^ ((ccol & 7) << 4);
                bf16x4 v = { (__bf16)acc[fm][fn][0], (__bf16)acc[fm][fn][1],
                             (__bf16)acc[fm][fn][2], (__bf16)acc[fm][fn][3] };
                *(bf16x4*)(wlds + addr) = v;
            }
        const int jb = (tileM & 1023) + wr * 128;
        __bf16* Wt = Ct + (size_t)batch * (1024 * 1024);
        #pragma unroll
        for (int pass = 0; pass < 16; ++pass) {
            const int fl  = pass * 4 + (lane >> 4);   // 0..63 (c-dim)
            const int jby = (lane & 15) * 16;         // byte offset in j-dim
            int addr = (fl * 256 + jby) ^ ((fl & 7) << 4);
            bf16x8 v = *(const bf16x8*)(wlds + addr);
            const int fg = tileN + wc * 64 + fl;
            *(bf16x8*)((char*)(Wt + (size_t)fg * 1024 + jb) + jby) = v;
        }
    }
#undef STAGE
#undef RD
#undef RDA
#undef RDB
#undef MF16
}

// ---------------------------------------------------------------------------
// Fused: read h/hx/ho once; emit h_bf (bf16) + all 4 row-score arrays.
// sSrc = h.wa1 ; sDst = h.wa2 + hreact.v + c.  One block per row.
// ---------------------------------------------------------------------------
__global__ __launch_bounds__(256) void fuse_h(
    const float* __restrict__ h, const float* __restrict__ hx, const float* __restrict__ ho,
    const float* __restrict__ wa, const float* __restrict__ vSS, const float* __restrict__ vDS,
    const float* __restrict__ cv, __bf16* __restrict__ h_bf,
    float* __restrict__ sSrcSS, float* __restrict__ sDstSS,
    float* __restrict__ sSrcDS, float* __restrict__ sDstDS)
{
    const int row = blockIdx.x;
    const int t = threadIdx.x;
    float4 hv = ((const float4*)(h  + (size_t)row * FF))[t];
    float4 xv = ((const float4*)(hx + (size_t)row * FF))[t];
    float4 ov = ((const float4*)(ho + (size_t)row * FF))[t];

    bf16x4 hb = { (__bf16)hv.x, (__bf16)hv.y, (__bf16)hv.z, (__bf16)hv.w };
    *(bf16x4*)&h_bf[(size_t)row * FF + t * 4] = hb;

    float4 w0 = ((const float4*)wa)[t];
    float4 w1 = ((const float4*)(wa + FF))[t];
    float4 w2 = ((const float4*)(wa + 2 * FF))[t];
    float4 w3 = ((const float4*)(wa + 3 * FF))[t];
    float4 vs = ((const float4*)vSS)[t];
    float4 vd = ((const float4*)vDS)[t];
    float d0 = hv.x * w0.x + hv.y * w0.y + hv.z * w0.z + hv.w * w0.w;
    float d1 = hv.x * w1.x + hv.y * w1.y + hv.z * w1.z + hv.w * w1.w;
    float d2 = hv.x * w2.x + hv.y * w2.y + hv.z * w2.z + hv.w * w2.w;
    float d3 = hv.x * w3.x + hv.y * w3.y + hv.z * w3.z + hv.w * w3.w;
    float d4 = xv.x * vs.x + xv.y * vs.y + xv.z * vs.z + xv.w * vs.w;
    float d5 = ov.x * vd.x + ov.y * vd.y + ov.z * vd.z + ov.w * vd.w;
    d0 = waveReduceSum(d0); d1 = waveReduceSum(d1); d2 = waveReduceSum(d2);
    d3 = waveReduceSum(d3); d4 = waveReduceSum(d4); d5 = waveReduceSum(d5);
    __shared__ float red[4][6];
    int wid = t >> 6;
    if ((t & 63) == 0) {
        red[wid][0] = d0; red[wid][1] = d1; red[wid][2] = d2;
        red[wid][3] = d3; red[wid][4] = d4; red[wid][5] = d5;
    }
    __syncthreads();
    if (t == 0) {
        float s0 = 0, s1 = 0, s2 = 0, s3 = 0, s4 = 0, s5 = 0;
        for (int w = 0; w < 4; ++w) {
            s0 += red[w][0]; s1 += red[w][1]; s2 += red[w][2];
            s3 += red[w][3]; s4 += red[w][4]; s5 += red[w][5];
        }
        sSrcSS[row] = s0;
        sDstSS[row] = s1 + s4 + cv[0];
        sSrcDS[row] = s2;
        sDstDS[row] = s3 + s5 + cv[1];
    }
}

// Transpose + convert: in [R][C] fp32 -> out [C][R] bf16 (used for W only).
__global__ __launch_bounds__(256) void transpose_cvt(
    const float* __restrict__ in, __bf16* __restrict__ out, int R, int C)
{
    const float* ib = in;
    __bf16* ob = out;
    const int r0 = blockIdx.y * 64;
    const int c0 = blockIdx.x * 64;
    __shared__ __bf16 t[64][66];
    #pragma unroll
    for (int it = 0; it < 16; ++it) {
        int idx = threadIdx.x + it * 256;
        int r = idx >> 6, c = idx & 63;
        t[r][c] = (__bf16)ib[(size_t)(r0 + r) * C + c0 + c];
    }
    __syncthreads();
    #pragma unroll
    for (int it = 0; it < 4; ++it) {
        int idx = threadIdx.x + it * 256;
        int rr = idx >> 4;
        int cc = (idx & 15) * 4;
        bf16x4 v = { t[cc][rr], t[cc + 1][rr], t[cc + 2][rr], t[cc + 3][rr] };
        *(bf16x4*)&ob[(size_t)(c0 + rr) * R + r0 + cc] = v;
    }
}

// wa[q][i], q in {a1SS, a2SS, a1DS, a2DS}: wa_q = W @ a_q  (row dots).
__global__ __launch_bounds__(256) void prep_wa(
    const float* __restrict__ W, const float* __restrict__ aSS,
    const float* __restrict__ aDS, float* __restrict__ wa)
{
    const int i = blockIdx.x;
    const int t = threadIdx.x;
    float4 w  = ((const float4*)(W + (size_t)i * FF))[t];
    float4 s1 = ((const float4*)aSS)[t];
    float4 s2 = ((const float4*)(aSS + FF))[t];
    float4 d1 = ((const float4*)aDS)[t];
    float4 d2 = ((const float4*)(aDS + FF))[t];
    float v0 = w.x * s1.x + w.y * s1.y + w.z * s1.z + w.w * s1.w;
    float v1 = w.x * s2.x + w.y * s2.y + w.z * s2.z + w.w * s2.w;
    float v2 = w.x * d1.x + w.y * d1.y + w.z * d1.z + w.w * d1.w;
    float v3 = w.x * d2.x + w.y * d2.y + w.z * d2.z + w.w * d2.w;
    v0 = waveReduceSum(v0); v1 = waveReduceSum(v1);
    v2 = waveReduceSum(v2); v3 = waveReduceSum(v3);
    __shared__ float red[4][4];
    int wid = t >> 6;
    if ((t & 63) == 0) { red[wid][0] = v0; red[wid][1] = v1; red[wid][2] = v2; red[wid][3] = v3; }
    __syncthreads();
    if (t < 4) {
        float s = red[0][t] + red[1][t] + red[2][t] + red[3][t];
        wa[(size_t)t * FF + i] = s;
    }
}

// v = csk_W^T @ a2 for SS and DS.
__global__ __launch_bounds__(256) void prep_v(
    const float* __restrict__ cskW, const float* __restrict__ aSS,
    const float* __restrict__ aDS, float* __restrict__ vSS, float* __restrict__ vDS)
{
    const int g0 = blockIdx.x * 64;
    const int gl = threadIdx.x & 63;
    const int fs = threadIdx.x >> 6;
    const int g = g0 + gl;
    float aS = 0.f, aD = 0.f;
    for (int f = fs * 256; f < fs * 256 + 256; ++f) {
        float w = cskW[(size_t)f * FF + g];
        aS += w * aSS[FF + f];
        aD += w * aDS[FF + f];
    }
    __shared__ float rS[4][64], rD[4][64];
    rS[fs][gl] = aS; rD[fs][gl] = aD;
    __syncthreads();
    if (fs == 0) {
        vSS[g] = rS[0][gl] + rS[1][gl] + rS[2][gl] + rS[3][gl];
        vDS[g] = rD[0][gl] + rD[1][gl] + rD[2][gl] + rD[3][gl];
    }
}

__global__ __launch_bounds__(256) void prep_c(
    const float* __restrict__ cskb, const float* __restrict__ aSS,
    const float* __restrict__ aDS, float* __restrict__ cv)
{
    int t = threadIdx.x;
    float cS = 0.f, cD = 0.f;
    for (int f = t; f < FF; f += 256) {
        float bb = cskb[f];
        cS += bb * aSS[FF + f];
        cD += bb * aDS[FF + f];
    }
    cS = waveReduceSum(cS);
    cD = waveReduceSum(cD);
    __shared__ float rA[4], rB[4];
    int wid = t >> 6;
    if ((t & 63) == 0) { rA[wid] = cS; rB[wid] = cD; }
    __syncthreads();
    if (t == 0) {
        cv[0] = rA[0] + rA[1] + rA[2] + rA[3];
        cv[1] = rB[0] + rB[1] + rB[2] + rB[3];
    }
}

// Row softmax -> att (bf16).
__global__ __launch_bounds__(256) void softmax_att(
    const float* __restrict__ mx, const float* __restrict__ mo,
    const float* __restrict__ sSrcSS, const float* __restrict__ sDstSS,
    const float* __restrict__ sSrcDS, const float* __restrict__ sDstDS,
    __bf16* __restrict__ att)
{
    const int row = blockIdx.x;
    const int base = row & ~(NN - 1);
    const int t = threadIdx.x;
    const float srcS = sSrcSS[row];
    const float srcD = sSrcDS[row];
    const float4* mxr = (const float4*)(mx + (size_t)row * NN);
    const float4* mor = (const float4*)(mo + (size_t)row * NN);
    const float4* dSp = (const float4*)(sDstSS + base);
    const float4* dDp = (const float4*)(sDstDS + base);

    float4 a = mxr[t], o = mor[t], dS = dSp[t], dD = dDp[t];
    const float* ap = (const float*)&a;
    const float* op = (const float*)&o;
    const float* sp = (const float*)&dS;
    const float* dp = (const float*)&dD;

    float ev[4];
    float m = -INFINITY;
    #pragma unroll
    for (int l = 0; l < 4; ++l) {
        float eS = srcS + sp[l];
        float lS = (eS >= 0.f) ? eS : ALPHA * eS;
        float eD = srcD + dp[l];
        float lD = (eD >= 0.f) ? eD : ALPHA * eD;
        float val = (ap[l] > 0.f) ? (lS * ap[l] + lD * op[l]) : NEG_INF;
        ev[l] = val;
        m = fmaxf(m, val);
    }
    m = waveReduceMax(m);
    __shared__ float redA[4], redB[4];
    int wid = t >> 6;
    if ((t & 63) == 0) redA[wid] = m;
    __syncthreads();
    float bm = fmaxf(fmaxf(redA[0], redA[1]), fmaxf(redA[2], redA[3]));

    float s = 0.f;
    #pragma unroll
    for (int l = 0; l < 4; ++l) {
        float p = expf(ev[l] - bm);
        ev[l] = p;
        s += p;
    }
    s = waveReduceSum(s);
    if ((t & 63) == 0) redB[wid] = s;
    __syncthreads();
    float bs = redB[0] + redB[1] + redB[2] + redB[3];
    float inv = 1.f / bs;

    bf16x4 v = { (__bf16)(ev[0] * inv), (__bf16)(ev[1] * inv),
                 (__bf16)(ev[2] * inv), (__bf16)(ev[3] * inv) };
    *(bf16x4*)&att[(size_t)row * NN + t * 4] = v;
}

// ---------------------------------------------------------------------------
extern "C" void kernel_launch(void* const* d_in, const int* in_sizes, int n_in,
                              void* d_out, int out_size, void* d_ws, size_t ws_size,
                              hipStream_t stream)
{
    const float* h    = (const float*)d_in[0];
    const float* hx   = (const float*)d_in[1];
    const float* ho   = (const float*)d_in[2];
    const float* mx   = (const float*)d_in[3];
    const float* mo   = (const float*)d_in[4];
    const float* W    = (const float*)d_in[5];
    const float* aSS  = (const float*)d_in[6];
    const float* aDS  = (const float*)d_in[7];
    const float* cskW = (const float*)d_in[8];
    const float* cskb = (const float*)d_in[9];
    float* out = (float*)d_out;

    char* ws = (char*)d_ws;
    const size_t MB = 1024 * 1024;
    __bf16* h_bf   = (__bf16*)ws;              // 32MB
    __bf16* WhT_bf = (__bf16*)(ws + 32 * MB);  // 32MB (per-batch [F][N] bf16)
    __bf16* att_bf = (__bf16*)(ws + 64 * MB);  // 32MB
    __bf16* WbfT   = (__bf16*)(ws + 96 * MB);  // 2MB
    float* wa     = (float*)(ws + 98 * MB);    // 16KB [4][FF]
    float* vSS    = wa + 4 * FF;
    float* vDS    = vSS + FF;
    float* cv     = vDS + FF;
    float* sSrcSS = cv + 64;
    float* sDstSS = sSrcSS + BZ * NN;
    float* sSrcDS = sDstSS + BZ * NN;
    float* sDstDS = sSrcDS + BZ * NN;

    // 1) small prep (fp32): wa = W@a vectors, v = cskW^T a2, c = b.a2
    prep_wa<<<FF, 256, 0, stream>>>(W, aSS, aDS, wa);
    prep_v<<<16, 256, 0, stream>>>(cskW, aSS, aDS, vSS, vDS);
    prep_c<<<1, 256, 0, stream>>>(cskb, aSS, aDS, cv);
    // 2) W -> W^T bf16
    transpose_cvt<<<dim3(16, 16, 1), 256, 0, stream>>>(W, WbfT, FF, FF);
    // 3) fused: h->bf16 + all row scores (reads h,hx,ho once)
    fuse_h<<<BZ * NN, 256, 0, stream>>>(h, hx, ho, wa, vSS, vDS, cv, h_bf,
                                        sSrcSS, sDstSS, sSrcDS, sDstDS);
    // 4) Wh^T bf16 = (h @ W)^T per batch (8-phase GEMM, C^T epilogue)
    gemm256<2><<<256, 512, 0, stream>>>(h_bf, WbfT, nullptr, WhT_bf, 0);
    // 5) softmax -> att bf16
    softmax_att<<<BZ * NN, 256, 0, stream>>>(mx, mo, sSrcSS, sDstSS, sSrcDS, sDstDS,
                                             att_bf);
    // 6) out = elu(att @ Wh)
    gemm256<1><<<256, 512, 0, stream>>>(att_bf, WhT_bf, out, nullptr,
                                        (size_t)NN * FF);
}